// Round 1
// baseline (87.552 us; speedup 1.0000x reference)
//
#include <hip/hip_runtime.h>

constexpr int BDIM = 512;
// log2(e) / tau  with tau = 0.01
constexpr float INV_TAU_LOG2E = 144.26950408889634f;

__global__ __launch_bounds__(512) void smoothap_rows(const float* __restrict__ scores,
                                                     const float* __restrict__ target,
                                                     float* __restrict__ ap_out) {
    const int q = blockIdx.x;
    const int i = threadIdx.x;

    __shared__ float2 sp[BDIM];   // {scores[q][j]*C, target[q][j] - (j==q)}
    __shared__ float red_r[8];
    __shared__ float red_t[8];

    const float s_i = scores[q * BDIM + i];
    const float t_i = target[q * BDIM + i];
    const float sic = s_i * INV_TAU_LOG2E;
    sp[i] = make_float2(sic, t_i - (i == q ? 1.0f : 0.0f));
    __syncthreads();

    // sigmoid((s_j - s_i)/tau) = 1 / (1 + exp2((s_i - s_j) * log2e / tau))
    float sum_all = 0.0f;   // sum over ALL j of sg (j==i term = 0.5, removed later)
    float sum_pos = 0.0f;   // sum over all j of sg * pos_mask[j]
#pragma unroll 8
    for (int j = 0; j < BDIM; ++j) {
        float2 v = sp[j];
        float e  = __builtin_amdgcn_exp2f(sic - v.x);
        float sg = __builtin_amdgcn_rcpf(1.0f + e);
        sum_all += sg;
        sum_pos  = fmaf(sg, v.y, sum_pos);
    }

    // sim_all_rk = (sum_all - 0.5) + 1 ; sim_pos_rk = (sum_pos + t_i) * t_i
    float ratio = t_i * (sum_pos + t_i) / (sum_all + 0.5f);
    float tv    = t_i;

#pragma unroll
    for (int off = 32; off > 0; off >>= 1) {
        ratio += __shfl_down(ratio, off, 64);
        tv    += __shfl_down(tv, off, 64);
    }
    const int lane = i & 63, wid = i >> 6;
    if (lane == 0) { red_r[wid] = ratio; red_t[wid] = tv; }
    __syncthreads();
    if (i == 0) {
        float r = 0.0f, t = 0.0f;
#pragma unroll
        for (int w = 0; w < 8; ++w) { r += red_r[w]; t += red_t[w]; }
        ap_out[q] = r / t;   // ap for query q
    }
}

__global__ __launch_bounds__(512) void smoothap_final(const float* __restrict__ ap,
                                                      float* __restrict__ out) {
    float v = ap[threadIdx.x];
#pragma unroll
    for (int off = 32; off > 0; off >>= 1) v += __shfl_down(v, off, 64);
    __shared__ float red[8];
    const int lane = threadIdx.x & 63, wid = threadIdx.x >> 6;
    if (lane == 0) red[wid] = v;
    __syncthreads();
    if (threadIdx.x == 0) {
        float s = 0.0f;
#pragma unroll
        for (int w = 0; w < 8; ++w) s += red[w];
        out[0] = 1.0f - s / 512.0f;
    }
}

extern "C" void kernel_launch(void* const* d_in, const int* in_sizes, int n_in,
                              void* d_out, int out_size, void* d_ws, size_t ws_size,
                              hipStream_t stream) {
    const float* scores = (const float*)d_in[0];
    const float* target = (const float*)d_in[1];
    float* ap  = (float*)d_ws;   // 512 floats of scratch
    float* out = (float*)d_out;

    hipLaunchKernelGGL(smoothap_rows, dim3(512), dim3(512), 0, stream, scores, target, ap);
    hipLaunchKernelGGL(smoothap_final, dim3(1), dim3(512), 0, stream, ap, out);
}